// Round 2
// baseline (604.441 us; speedup 1.0000x reference)
//
#include <hip/hip_runtime.h>
#include <hip/hip_bf16.h>

typedef unsigned short u16t;
typedef __attribute__((ext_vector_type(8))) short short8;
typedef __attribute__((ext_vector_type(8))) unsigned short ushort8;
typedef __attribute__((ext_vector_type(4))) unsigned short ushort4v;
typedef __attribute__((ext_vector_type(4))) float f32x4;

#define VTOT 1048576

__device__ __forceinline__ float bf2f(u16t u) {
  union { unsigned int i; float f; } v; v.i = ((unsigned int)u) << 16; return v.f;
}
__device__ __forceinline__ u16t f2bf(float f) {
  __hip_bfloat16 h = __float2bfloat16(f);
  union { __hip_bfloat16 b; u16t u; } v; v.b = h; return v.u;
}

// Kernel 1: sobel conv (bf16 LDS, fp32 accum) + fc0(relu) + fc1 via bf16 MFMA + stoch mask.
// R4 restructure: GEMM interleaved per z3-half-pass so ys holds only 128 voxels ->
// LDS 52.7KB -> 36.1KB -> 4 blocks/CU (lb(256,4)).  Per-mt full barriers replaced by
// wave-local lgkmcnt(0) fences (h buffer and ys A-fragments are wave-private).
// aws stores the z3-direction maxpool partial (computed from alpha_l in the flush),
// so nca_life only reduces over the 3x3 (z1,z2) rows.
__global__ __launch_bounds__(256, 4) void nca_main(
    const float* __restrict__ xg, const float* __restrict__ w0g,
    const float* __restrict__ b0g, const float* __restrict__ w1g,
    const float* __restrict__ stg, float* __restrict__ outg,
    float* __restrict__ aws, unsigned char* __restrict__ plife)
{
  __shared__ u16t xs[8704];          // [4][4][34][16] bf16 x halo (per pass); reused as h buffers
  __shared__ u16t ys[8192];          // [8 kchunks][128 voxels][8] bf16 y (per pass), MFMA-A layout
  __shared__ float st_l[256];        // stoch fp32
  __shared__ float alpha_l[256];     // fp32 alpha(x2), staged for z3-max + coalesced aws flush
  __shared__ unsigned char pl_l[256];// pre_life bits

  const int t = threadIdx.x;
  const int bid = blockIdx.x;
  const int b = bid >> 10;
  const int z1base = ((bid >> 5) & 31) * 2;
  const int z2base = (bid & 31) * 2;

  {
    int z1 = t >> 7, z2 = (t >> 6) & 1, z3 = t & 63;
    int gv = ((b * 64 + z1base + z1) * 64 + (z2base + z2)) * 64 + z3;
    st_l[t] = stg[gv];
  }

  #pragma unroll 1
  for (int p = 0; p < 2; ++p) {
    // keep the (loop-invariant) weight loads inside the loop: hoisting them would
    // extend their live range across the conv phase and blow the 128-VGPR budget
    asm volatile("" ::: "memory");
    if (p) __syncthreads();  // xs/ys WAR vs previous pass GEMM (h buffer lives in xs)
    // stage x halo (fp32 -> bf16): 544 rows x 16 ch = 2176 float4 chunks
    for (int it = 0; it < 9; ++it) {
      int q = t + it * 256;
      if (q < 2176) {
        int c4 = (q & 3) * 4, s = q >> 2;
        int i3 = s % 34, r = s / 34;
        int i2 = r & 3, i1 = r >> 2;
        int z1g = z1base + i1 - 1, z2g = z2base + i2 - 1, z3g = p * 32 + i3 - 1;
        f32x4 val = {0.f, 0.f, 0.f, 0.f};
        if ((unsigned)z1g < 64u && (unsigned)z2g < 64u && (unsigned)z3g < 64u) {
          int gv = ((b * 64 + z1g) * 64 + z2g) * 64 + z3g;
          val = *(const f32x4*)(xg + gv * 16 + c4);
        }
        ushort4v bv;
        #pragma unroll
        for (int j = 0; j < 4; ++j) bv[j] = f2bf(val[j]);
        *(ushort4v*)(xs + s * 16 + c4) = bv;
      }
    }
    __syncthreads();
    // conv: one (voxel, channel-half) per thread; 128 voxels this pass
    {
      const int hc = t & 1, vp = t >> 1;
      const int z1 = vp >> 6, z2 = (vp >> 5) & 1, z3l = vp & 31;
      float ax[8], ay[8], az[8];
      #pragma unroll
      for (int c = 0; c < 8; ++c) { ax[c] = 0.f; ay[c] = 0.f; az[c] = 0.f; }
      ushort8 ctr{};
      float amax = 0.0f;  // alpha>=0 in x; 0-pad gives same >0.1 verdict as -inf pad
      const float W[3] = {1.f, 2.f, 1.f};
      const float D[3] = {-1.f, 0.f, 1.f};
      #pragma unroll
      for (int d1 = 0; d1 < 3; ++d1)
        #pragma unroll
        for (int d2 = 0; d2 < 3; ++d2)
          #pragma unroll
          for (int d3 = 0; d3 < 3; ++d3) {
            const int base = (((z1 + d1) * 4 + (z2 + d2)) * 34 + (z3l + d3)) * 16 + hc * 8;
            ushort8 u = *(const ushort8*)(xs + base);
            float f[8];
            #pragma unroll
            for (int c = 0; c < 8; ++c) f[c] = bf2f((u16t)u[c]);
            const float cx = W[d1] * W[d2] * D[d3] * 0.03125f;  // kx[k,i,j]=w[k]w[i]d[j]/32
            const float cy = W[d1] * D[d2] * W[d3] * 0.03125f;  // ky=kx.T(0,2,1)
            const float cz = D[d1] * W[d2] * W[d3] * 0.03125f;  // kz=kx.T(2,1,0)
            if (cx != 0.f) {
              #pragma unroll
              for (int c = 0; c < 8; ++c) ax[c] = fmaf(f[c], cx, ax[c]);
            }
            if (cy != 0.f) {
              #pragma unroll
              for (int c = 0; c < 8; ++c) ay[c] = fmaf(f[c], cy, ay[c]);
            }
            if (cz != 0.f) {
              #pragma unroll
              for (int c = 0; c < 8; ++c) az[c] = fmaf(f[c], cz, az[c]);
            }
            if (d1 == 1 && d2 == 1 && d3 == 1) ctr = u;
            amax = fmaxf(amax, f[3]);  // alpha = ch3 (meaningful for hc==0)
          }
      *(ushort8*)(ys + (0 + hc) * 1024 + vp * 8) = ctr;
      ushort8 bx, by, bz;
      #pragma unroll
      for (int c = 0; c < 8; ++c) {
        bx[c] = (short)f2bf(ax[c]); by[c] = (short)f2bf(ay[c]); bz[c] = (short)f2bf(az[c]);
      }
      *(ushort8*)(ys + (2 + hc) * 1024 + vp * 8) = bx;
      *(ushort8*)(ys + (4 + hc) * 1024 + vp * 8) = by;
      *(ushort8*)(ys + (6 + hc) * 1024 + vp * 8) = bz;
      if (hc == 0) pl_l[z1 * 128 + z2 * 64 + p * 32 + z3l] = (amax > 0.1f) ? (unsigned char)1 : (unsigned char)0;
    }
    __syncthreads();  // cross-wave WAR: all conv halo reads of xs done before h-writes clobber xs

    // GEMM phase (this pass, M=128): per wave M=32 (2 m-tiles of 16)
    // fc0 K=64 N=128; fc1 K=128 N=16.  ys rows and h buffer are wave-private.
    {
      const int lane = t & 63, w = t >> 6;
      const int col = lane & 15, quad = lane >> 4;
      short8 w0f[2][8];  // B[k=kt*32+quad*8+j][n=nt*16+col] = w0[n][k], cvt fp32->bf16
      #pragma unroll
      for (int kt = 0; kt < 2; ++kt)
        #pragma unroll
        for (int nt = 0; nt < 8; ++nt) {
          const float* pw = w0g + (nt * 16 + col) * 64 + kt * 32 + quad * 8;
          f32x4 lo = *(const f32x4*)pw, hi = *(const f32x4*)(pw + 4);
          short8 fr;
          #pragma unroll
          for (int j = 0; j < 4; ++j) { fr[j] = (short)f2bf(lo[j]); fr[4 + j] = (short)f2bf(hi[j]); }
          w0f[kt][nt] = fr;
        }
      short8 w1f[4];     // B[k][n=col] = w1[col][k]
      #pragma unroll
      for (int kt = 0; kt < 4; ++kt) {
        const float* pw = w1g + col * 128 + kt * 32 + quad * 8;
        f32x4 lo = *(const f32x4*)pw, hi = *(const f32x4*)(pw + 4);
        short8 fr;
        #pragma unroll
        for (int j = 0; j < 4; ++j) { fr[j] = (short)f2bf(lo[j]); fr[4 + j] = (short)f2bf(hi[j]); }
        w1f[kt] = fr;
      }
      float bias[8];
      #pragma unroll
      for (int nt = 0; nt < 8; ++nt) bias[nt] = b0g[nt * 16 + col];

      u16t* hw = xs + w * 2176;  // per-wave h buffer [16][136]

      #pragma unroll
      for (int mt = 0; mt < 2; ++mt) {
        const int mbase = w * 32 + mt * 16;
        short8 aF[2];  // A[m=col][k=kt*32+quad*8+j] = y[mbase+col][k]
        #pragma unroll
        for (int kt = 0; kt < 2; ++kt)
          aF[kt] = *(const short8*)(ys + (kt * 4 + quad) * 1024 + (mbase + col) * 8);
        f32x4 acc[8];
        #pragma unroll
        for (int nt = 0; nt < 8; ++nt) {
          f32x4 tmp = {bias[nt], bias[nt], bias[nt], bias[nt]};
          acc[nt] = tmp;
        }
        #pragma unroll
        for (int kt = 0; kt < 2; ++kt)
          #pragma unroll
          for (int nt = 0; nt < 8; ++nt)
            acc[nt] = __builtin_amdgcn_mfma_f32_16x16x32_bf16(aF[kt], w0f[kt][nt], acc[nt], 0, 0, 0);
        // relu -> bf16 -> LDS (C layout -> A layout); h[m=quad*4+r][k=nt*16+col]
        #pragma unroll
        for (int nt = 0; nt < 8; ++nt)
          #pragma unroll
          for (int r = 0; r < 4; ++r)
            hw[(quad * 4 + r) * 136 + nt * 16 + col] = f2bf(fmaxf(acc[nt][r], 0.0f));
        // wave-local ordering only: hw is per-wave; DS ops complete in order after drain
        asm volatile("s_waitcnt lgkmcnt(0)" ::: "memory");
        __builtin_amdgcn_sched_barrier(0);
        f32x4 dxa = {0.f, 0.f, 0.f, 0.f};
        #pragma unroll
        for (int kt = 0; kt < 4; ++kt) {
          short8 ah = *(const short8*)(hw + col * 136 + kt * 32 + quad * 8);
          dxa = __builtin_amdgcn_mfma_f32_16x16x32_bf16(ah, w1f[kt], dxa, 0, 0, 0);
        }
        // epilogue: out[v][col] = x[v][col] + mask*dx (xg re-read is L2/L3-hot)
        #pragma unroll
        for (int r = 0; r < 4; ++r) {
          const int vp = mbase + quad * 4 + r;
          const int z1 = vp >> 6, z2 = (vp >> 5) & 1, z3l = vp & 31;
          const int v = z1 * 128 + z2 * 64 + p * 32 + z3l;
          const int gv = ((b * 64 + z1base + z1) * 64 + (z2base + z2)) * 64 + p * 32 + z3l;
          const int addr = gv * 16 + col;
          float dx = (st_l[v] > 0.5f) ? dxa[r] : 0.0f;
          float x2 = xg[addr] + dx;
          outg[addr] = x2;
          if (col == 3) alpha_l[v] = x2;  // stage fp32 alpha(x2) in LDS
        }
      }
    }
  }
  __syncthreads();
  // coalesced aux flush; fold the z3 direction of the alive maxpool here:
  // aws[gv] = max(alpha[z3-1], alpha[z3], alpha[z3+1]) (domain edges -> -1e30 sentinel)
  if (aws != nullptr) {
    const int v = t, z3 = t & 63;
    const float a = alpha_l[v];
    const float up = (z3 > 0) ? alpha_l[v - 1] : -1e30f;
    const float dn = (z3 < 63) ? alpha_l[v + 1] : -1e30f;
    const int gv = ((b * 64 + z1base + (v >> 7)) * 64 + (z2base + ((v >> 6) & 1))) * 64 + z3;
    aws[gv] = fmaxf(a, fmaxf(up, dn));
    plife[gv] = pl_l[v];
  }
}

// Kernel 2: life = plife & (max over 3x3 (z1,z2) rows of z3-premaxed aws > 0.1);
// zero dead voxels in out.  Staging is 16 fully-coalesced 256B rows, no div/mod.
__global__ void nca_life(const float* __restrict__ aws,
                         const unsigned char* __restrict__ plife,
                         float* __restrict__ og)
{
  __shared__ float m3s[1024];  // [16 rows][64] z3-premaxed alpha(x2)
  const int t = threadIdx.x, bid = blockIdx.x;
  const int b = bid >> 10;
  const int z1base = ((bid >> 5) & 31) * 2;
  const int z2base = (bid & 31) * 2;
  #pragma unroll
  for (int it = 0; it < 4; ++it) {
    const int row = it * 4 + (t >> 6), z3 = t & 63;
    const int z1g = z1base + (row >> 2) - 1, z2g = z2base + (row & 3) - 1;
    float a = -1e30f;
    if ((unsigned)z1g < 64u && (unsigned)z2g < 64u)
      a = aws[((b * 64 + z1g) * 64 + z2g) * 64 + z3];
    m3s[row * 64 + z3] = a;
  }
  const int z1 = t >> 7, z2 = (t >> 6) & 1, z3 = t & 63;
  const int gv = ((b * 64 + z1base + z1) * 64 + (z2base + z2)) * 64 + z3;
  const unsigned char pl = plife[gv];  // issue early, hide under barrier
  __syncthreads();
  float mo = -1e30f;
  #pragma unroll
  for (int d1 = 0; d1 < 3; ++d1)
    #pragma unroll
    for (int d2 = 0; d2 < 3; ++d2)
      mo = fmaxf(mo, m3s[((z1 + d1) * 4 + (z2 + d2)) * 64 + z3]);
  const bool life = (pl != 0) && (mo > 0.1f);
  if (!life) {
    f32x4 z = {0.f, 0.f, 0.f, 0.f};
    #pragma unroll
    for (int j = 0; j < 4; ++j) *(f32x4*)(og + gv * 16 + j * 4) = z;
  }
}

// Fallback (no workspace): recompute both alive masks from strided global reads.
__global__ void nca_life_strided(const float* __restrict__ xg, const float* __restrict__ outg,
                                 float* __restrict__ og)
{
  __shared__ float a2x[1056];
  __shared__ float a2o[1056];
  const int t = threadIdx.x, bid = blockIdx.x;
  const int b = bid >> 10;
  const int z1base = ((bid >> 5) & 31) * 2;
  const int z2base = (bid & 31) * 2;
  for (int it = 0; it < 5; ++it) {
    int q = t + it * 256;
    if (q < 1056) {
      int i3 = q % 66, r = q / 66;
      int i2 = r & 3, i1 = r >> 2;
      int z1g = z1base + i1 - 1, z2g = z2base + i2 - 1, z3g = i3 - 1;
      float vx = 0.f, vo = 0.f;
      if ((unsigned)z1g < 64u && (unsigned)z2g < 64u && (unsigned)z3g < 64u) {
        int gv = ((b * 64 + z1g) * 64 + z2g) * 64 + z3g;
        vx = xg[gv * 16 + 3];
        vo = outg[gv * 16 + 3];
      }
      a2x[q] = vx; a2o[q] = vo;
    }
  }
  __syncthreads();
  const int z1 = t >> 7, z2 = (t >> 6) & 1, z3 = t & 63;
  float mx = -1e30f, mo = -1e30f;
  #pragma unroll
  for (int d1 = 0; d1 < 3; ++d1)
    #pragma unroll
    for (int d2 = 0; d2 < 3; ++d2)
      #pragma unroll
      for (int d3 = 0; d3 < 3; ++d3) {
        const int idx = ((z1 + d1) * 4 + (z2 + d2)) * 66 + (z3 + d3);
        mx = fmaxf(mx, a2x[idx]);
        mo = fmaxf(mo, a2o[idx]);
      }
  const bool life = (mx > 0.1f) && (mo > 0.1f);
  if (!life) {
    const int gv = ((b * 64 + z1base + z1) * 64 + (z2base + z2)) * 64 + z3;
    f32x4 z = {0.f, 0.f, 0.f, 0.f};
    #pragma unroll
    for (int j = 0; j < 4; ++j) *(f32x4*)(og + gv * 16 + j * 4) = z;
  }
}

extern "C" void kernel_launch(void* const* d_in, const int* in_sizes, int n_in,
                              void* d_out, int out_size, void* d_ws, size_t ws_size,
                              hipStream_t stream) {
  (void)out_size;
  const void *px = nullptr, *pw0 = nullptr, *pb0 = nullptr, *pw1 = nullptr, *pst = nullptr;
  for (int i = 0; i < n_in; ++i) {
    switch (in_sizes[i]) {
      case 16777216: px  = d_in[i]; break;  // x  [4,64,64,64,16]
      case 8192:     pw0 = d_in[i]; break;  // w0 [128,64]
      case 128:      pb0 = d_in[i]; break;  // b0 [128]
      case 2048:     pw1 = d_in[i]; break;  // w1 [16,128]
      case 1048576:  pst = d_in[i]; break;  // stoch [4,64,64,64,1]
    }
  }
  if (!px || !pw0 || !pb0 || !pw1 || !pst) {
    px = d_in[0]; pw0 = d_in[1]; pb0 = d_in[2]; pw1 = d_in[3]; pst = d_in[4];
  }
  float* outg = (float*)d_out;
  const size_t need = (size_t)VTOT * 4 + (size_t)VTOT;  // fp32 z3-max alpha + byte plife
  const bool use_ws = (d_ws != nullptr) && (ws_size >= need);
  float* aws = use_ws ? (float*)d_ws : nullptr;
  unsigned char* plife = use_ws ? ((unsigned char*)d_ws + (size_t)VTOT * 4) : nullptr;

  nca_main<<<4096, 256, 0, stream>>>((const float*)px, (const float*)pw0, (const float*)pb0,
                                     (const float*)pw1, (const float*)pst, outg, aws, plife);
  if (use_ws)
    nca_life<<<4096, 256, 0, stream>>>(aws, plife, outg);
  else
    nca_life_strided<<<4096, 256, 0, stream>>>((const float*)px, outg, outg);
}

// Round 3
// 357.223 us; speedup vs baseline: 1.6921x; 1.6921x over previous
//
#include <hip/hip_runtime.h>
#include <hip/hip_bf16.h>

typedef unsigned short u16t;
typedef __attribute__((ext_vector_type(8))) short short8;
typedef __attribute__((ext_vector_type(8))) unsigned short ushort8;
typedef __attribute__((ext_vector_type(4))) unsigned short ushort4v;
typedef __attribute__((ext_vector_type(4))) float f32x4;

#define VTOT 1048576

__device__ __forceinline__ float bf2f(u16t u) {
  union { unsigned int i; float f; } v; v.i = ((unsigned int)u) << 16; return v.f;
}
__device__ __forceinline__ u16t f2bf(float f) {
  __hip_bfloat16 h = __float2bfloat16(f);
  union { __hip_bfloat16 b; u16t u; } v; v.b = h; return v.u;
}

// Kernel 1: sobel conv (bf16 LDS, fp32 accum) + fc0(relu) + fc1 via bf16 MFMA + stoch mask.
// R5: keep the R4 structure (GEMM interleaved per z3-half-pass, LDS 36.1KB, wave-local
// fences, z3-maxpool folded into the flush) but revert to lb(256,2).
// R4 post-mortem: lb(256,4) forced VGPR 100->64 -> ~1.6GB scratch spill traffic
// (FETCH 67->751MB, WRITE 71->968MB), 530us.  At VGPR~100 the HW occupancy step
// (<=128) already gives 4 waves/SIMD, and LDS 36.3KB allows 4 blocks/CU — the
// launch-bounds floor must NOT constrain the allocator below actual need.
__global__ __launch_bounds__(256, 2) void nca_main(
    const float* __restrict__ xg, const float* __restrict__ w0g,
    const float* __restrict__ b0g, const float* __restrict__ w1g,
    const float* __restrict__ stg, float* __restrict__ outg,
    float* __restrict__ aws, unsigned char* __restrict__ plife)
{
  __shared__ u16t xs[8704];          // [4][4][34][16] bf16 x halo (per pass); reused as h buffers
  __shared__ u16t ys[8192];          // [8 kchunks][128 voxels][8] bf16 y (per pass), MFMA-A layout
  __shared__ float st_l[256];        // stoch fp32
  __shared__ float alpha_l[256];     // fp32 alpha(x2), staged for z3-max + coalesced aws flush
  __shared__ unsigned char pl_l[256];// pre_life bits

  const int t = threadIdx.x;
  const int bid = blockIdx.x;
  const int b = bid >> 10;
  const int z1base = ((bid >> 5) & 31) * 2;
  const int z2base = (bid & 31) * 2;

  {
    int z1 = t >> 7, z2 = (t >> 6) & 1, z3 = t & 63;
    int gv = ((b * 64 + z1base + z1) * 64 + (z2base + z2)) * 64 + z3;
    st_l[t] = stg[gv];
  }

  #pragma unroll 1
  for (int p = 0; p < 2; ++p) {
    // keep the (loop-invariant) weight loads inside the loop: hoisting them would
    // extend their live range across the conv phase and inflate VGPR pressure
    asm volatile("" ::: "memory");
    if (p) __syncthreads();  // xs/ys WAR vs previous pass GEMM (h buffer lives in xs)
    // stage x halo (fp32 -> bf16): 544 rows x 16 ch = 2176 float4 chunks
    for (int it = 0; it < 9; ++it) {
      int q = t + it * 256;
      if (q < 2176) {
        int c4 = (q & 3) * 4, s = q >> 2;
        int i3 = s % 34, r = s / 34;
        int i2 = r & 3, i1 = r >> 2;
        int z1g = z1base + i1 - 1, z2g = z2base + i2 - 1, z3g = p * 32 + i3 - 1;
        f32x4 val = {0.f, 0.f, 0.f, 0.f};
        if ((unsigned)z1g < 64u && (unsigned)z2g < 64u && (unsigned)z3g < 64u) {
          int gv = ((b * 64 + z1g) * 64 + z2g) * 64 + z3g;
          val = *(const f32x4*)(xg + gv * 16 + c4);
        }
        ushort4v bv;
        #pragma unroll
        for (int j = 0; j < 4; ++j) bv[j] = f2bf(val[j]);
        *(ushort4v*)(xs + s * 16 + c4) = bv;
      }
    }
    __syncthreads();
    // conv: one (voxel, channel-half) per thread; 128 voxels this pass
    {
      const int hc = t & 1, vp = t >> 1;
      const int z1 = vp >> 6, z2 = (vp >> 5) & 1, z3l = vp & 31;
      float ax[8], ay[8], az[8];
      #pragma unroll
      for (int c = 0; c < 8; ++c) { ax[c] = 0.f; ay[c] = 0.f; az[c] = 0.f; }
      ushort8 ctr{};
      float amax = 0.0f;  // alpha>=0 in x; 0-pad gives same >0.1 verdict as -inf pad
      const float W[3] = {1.f, 2.f, 1.f};
      const float D[3] = {-1.f, 0.f, 1.f};
      #pragma unroll
      for (int d1 = 0; d1 < 3; ++d1)
        #pragma unroll
        for (int d2 = 0; d2 < 3; ++d2)
          #pragma unroll
          for (int d3 = 0; d3 < 3; ++d3) {
            const int base = (((z1 + d1) * 4 + (z2 + d2)) * 34 + (z3l + d3)) * 16 + hc * 8;
            ushort8 u = *(const ushort8*)(xs + base);
            float f[8];
            #pragma unroll
            for (int c = 0; c < 8; ++c) f[c] = bf2f((u16t)u[c]);
            const float cx = W[d1] * W[d2] * D[d3] * 0.03125f;  // kx[k,i,j]=w[k]w[i]d[j]/32
            const float cy = W[d1] * D[d2] * W[d3] * 0.03125f;  // ky=kx.T(0,2,1)
            const float cz = D[d1] * W[d2] * W[d3] * 0.03125f;  // kz=kx.T(2,1,0)
            if (cx != 0.f) {
              #pragma unroll
              for (int c = 0; c < 8; ++c) ax[c] = fmaf(f[c], cx, ax[c]);
            }
            if (cy != 0.f) {
              #pragma unroll
              for (int c = 0; c < 8; ++c) ay[c] = fmaf(f[c], cy, ay[c]);
            }
            if (cz != 0.f) {
              #pragma unroll
              for (int c = 0; c < 8; ++c) az[c] = fmaf(f[c], cz, az[c]);
            }
            if (d1 == 1 && d2 == 1 && d3 == 1) ctr = u;
            amax = fmaxf(amax, f[3]);  // alpha = ch3 (meaningful for hc==0)
          }
      *(ushort8*)(ys + (0 + hc) * 1024 + vp * 8) = ctr;
      ushort8 bx, by, bz;
      #pragma unroll
      for (int c = 0; c < 8; ++c) {
        bx[c] = (short)f2bf(ax[c]); by[c] = (short)f2bf(ay[c]); bz[c] = (short)f2bf(az[c]);
      }
      *(ushort8*)(ys + (2 + hc) * 1024 + vp * 8) = bx;
      *(ushort8*)(ys + (4 + hc) * 1024 + vp * 8) = by;
      *(ushort8*)(ys + (6 + hc) * 1024 + vp * 8) = bz;
      if (hc == 0) pl_l[z1 * 128 + z2 * 64 + p * 32 + z3l] = (amax > 0.1f) ? (unsigned char)1 : (unsigned char)0;
    }
    __syncthreads();  // cross-wave WAR: all conv halo reads of xs done before h-writes clobber xs

    // GEMM phase (this pass, M=128): per wave M=32 (2 m-tiles of 16)
    // fc0 K=64 N=128; fc1 K=128 N=16.  ys rows and h buffer are wave-private.
    {
      const int lane = t & 63, w = t >> 6;
      const int col = lane & 15, quad = lane >> 4;
      short8 w0f[2][8];  // B[k=kt*32+quad*8+j][n=nt*16+col] = w0[n][k], cvt fp32->bf16
      #pragma unroll
      for (int kt = 0; kt < 2; ++kt)
        #pragma unroll
        for (int nt = 0; nt < 8; ++nt) {
          const float* pw = w0g + (nt * 16 + col) * 64 + kt * 32 + quad * 8;
          f32x4 lo = *(const f32x4*)pw, hi = *(const f32x4*)(pw + 4);
          short8 fr;
          #pragma unroll
          for (int j = 0; j < 4; ++j) { fr[j] = (short)f2bf(lo[j]); fr[4 + j] = (short)f2bf(hi[j]); }
          w0f[kt][nt] = fr;
        }
      short8 w1f[4];     // B[k][n=col] = w1[col][k]
      #pragma unroll
      for (int kt = 0; kt < 4; ++kt) {
        const float* pw = w1g + col * 128 + kt * 32 + quad * 8;
        f32x4 lo = *(const f32x4*)pw, hi = *(const f32x4*)(pw + 4);
        short8 fr;
        #pragma unroll
        for (int j = 0; j < 4; ++j) { fr[j] = (short)f2bf(lo[j]); fr[4 + j] = (short)f2bf(hi[j]); }
        w1f[kt] = fr;
      }
      float bias[8];
      #pragma unroll
      for (int nt = 0; nt < 8; ++nt) bias[nt] = b0g[nt * 16 + col];

      u16t* hw = xs + w * 2176;  // per-wave h buffer [16][136]

      #pragma unroll
      for (int mt = 0; mt < 2; ++mt) {
        const int mbase = w * 32 + mt * 16;
        short8 aF[2];  // A[m=col][k=kt*32+quad*8+j] = y[mbase+col][k]
        #pragma unroll
        for (int kt = 0; kt < 2; ++kt)
          aF[kt] = *(const short8*)(ys + (kt * 4 + quad) * 1024 + (mbase + col) * 8);
        f32x4 acc[8];
        #pragma unroll
        for (int nt = 0; nt < 8; ++nt) {
          f32x4 tmp = {bias[nt], bias[nt], bias[nt], bias[nt]};
          acc[nt] = tmp;
        }
        #pragma unroll
        for (int kt = 0; kt < 2; ++kt)
          #pragma unroll
          for (int nt = 0; nt < 8; ++nt)
            acc[nt] = __builtin_amdgcn_mfma_f32_16x16x32_bf16(aF[kt], w0f[kt][nt], acc[nt], 0, 0, 0);
        // relu -> bf16 -> LDS (C layout -> A layout); h[m=quad*4+r][k=nt*16+col]
        #pragma unroll
        for (int nt = 0; nt < 8; ++nt)
          #pragma unroll
          for (int r = 0; r < 4; ++r)
            hw[(quad * 4 + r) * 136 + nt * 16 + col] = f2bf(fmaxf(acc[nt][r], 0.0f));
        // wave-local ordering only: hw is per-wave; DS ops complete in order after drain
        asm volatile("s_waitcnt lgkmcnt(0)" ::: "memory");
        __builtin_amdgcn_sched_barrier(0);
        f32x4 dxa = {0.f, 0.f, 0.f, 0.f};
        #pragma unroll
        for (int kt = 0; kt < 4; ++kt) {
          short8 ah = *(const short8*)(hw + col * 136 + kt * 32 + quad * 8);
          dxa = __builtin_amdgcn_mfma_f32_16x16x32_bf16(ah, w1f[kt], dxa, 0, 0, 0);
        }
        // epilogue: out[v][col] = x[v][col] + mask*dx (xg re-read is L2/L3-hot)
        #pragma unroll
        for (int r = 0; r < 4; ++r) {
          const int vp = mbase + quad * 4 + r;
          const int z1 = vp >> 6, z2 = (vp >> 5) & 1, z3l = vp & 31;
          const int v = z1 * 128 + z2 * 64 + p * 32 + z3l;
          const int gv = ((b * 64 + z1base + z1) * 64 + (z2base + z2)) * 64 + p * 32 + z3l;
          const int addr = gv * 16 + col;
          float dx = (st_l[v] > 0.5f) ? dxa[r] : 0.0f;
          float x2 = xg[addr] + dx;
          outg[addr] = x2;
          if (col == 3) alpha_l[v] = x2;  // stage fp32 alpha(x2) in LDS
        }
      }
    }
  }
  __syncthreads();
  // coalesced aux flush; fold the z3 direction of the alive maxpool here:
  // aws[gv] = max(alpha[z3-1], alpha[z3], alpha[z3+1]) (domain edges -> -1e30 sentinel)
  if (aws != nullptr) {
    const int v = t, z3 = t & 63;
    const float a = alpha_l[v];
    const float up = (z3 > 0) ? alpha_l[v - 1] : -1e30f;
    const float dn = (z3 < 63) ? alpha_l[v + 1] : -1e30f;
    const int gv = ((b * 64 + z1base + (v >> 7)) * 64 + (z2base + ((v >> 6) & 1))) * 64 + z3;
    aws[gv] = fmaxf(a, fmaxf(up, dn));
    plife[gv] = pl_l[v];
  }
}

// Kernel 2: life = plife & (max over 3x3 (z1,z2) rows of z3-premaxed aws > 0.1);
// zero dead voxels in out.  Staging is 16 fully-coalesced 256B rows, no div/mod.
__global__ void nca_life(const float* __restrict__ aws,
                         const unsigned char* __restrict__ plife,
                         float* __restrict__ og)
{
  __shared__ float m3s[1024];  // [16 rows][64] z3-premaxed alpha(x2)
  const int t = threadIdx.x, bid = blockIdx.x;
  const int b = bid >> 10;
  const int z1base = ((bid >> 5) & 31) * 2;
  const int z2base = (bid & 31) * 2;
  #pragma unroll
  for (int it = 0; it < 4; ++it) {
    const int row = it * 4 + (t >> 6), z3 = t & 63;
    const int z1g = z1base + (row >> 2) - 1, z2g = z2base + (row & 3) - 1;
    float a = -1e30f;
    if ((unsigned)z1g < 64u && (unsigned)z2g < 64u)
      a = aws[((b * 64 + z1g) * 64 + z2g) * 64 + z3];
    m3s[row * 64 + z3] = a;
  }
  const int z1 = t >> 7, z2 = (t >> 6) & 1, z3 = t & 63;
  const int gv = ((b * 64 + z1base + z1) * 64 + (z2base + z2)) * 64 + z3;
  const unsigned char pl = plife[gv];  // issue early, hide under barrier
  __syncthreads();
  float mo = -1e30f;
  #pragma unroll
  for (int d1 = 0; d1 < 3; ++d1)
    #pragma unroll
    for (int d2 = 0; d2 < 3; ++d2)
      mo = fmaxf(mo, m3s[((z1 + d1) * 4 + (z2 + d2)) * 64 + z3]);
  const bool life = (pl != 0) && (mo > 0.1f);
  if (!life) {
    f32x4 z = {0.f, 0.f, 0.f, 0.f};
    #pragma unroll
    for (int j = 0; j < 4; ++j) *(f32x4*)(og + gv * 16 + j * 4) = z;
  }
}

// Fallback (no workspace): recompute both alive masks from strided global reads.
__global__ void nca_life_strided(const float* __restrict__ xg, const float* __restrict__ outg,
                                 float* __restrict__ og)
{
  __shared__ float a2x[1056];
  __shared__ float a2o[1056];
  const int t = threadIdx.x, bid = blockIdx.x;
  const int b = bid >> 10;
  const int z1base = ((bid >> 5) & 31) * 2;
  const int z2base = (bid & 31) * 2;
  for (int it = 0; it < 5; ++it) {
    int q = t + it * 256;
    if (q < 1056) {
      int i3 = q % 66, r = q / 66;
      int i2 = r & 3, i1 = r >> 2;
      int z1g = z1base + i1 - 1, z2g = z2base + i2 - 1, z3g = i3 - 1;
      float vx = 0.f, vo = 0.f;
      if ((unsigned)z1g < 64u && (unsigned)z2g < 64u && (unsigned)z3g < 64u) {
        int gv = ((b * 64 + z1g) * 64 + z2g) * 64 + z3g;
        vx = xg[gv * 16 + 3];
        vo = outg[gv * 16 + 3];
      }
      a2x[q] = vx; a2o[q] = vo;
    }
  }
  __syncthreads();
  const int z1 = t >> 7, z2 = (t >> 6) & 1, z3 = t & 63;
  float mx = -1e30f, mo = -1e30f;
  #pragma unroll
  for (int d1 = 0; d1 < 3; ++d1)
    #pragma unroll
    for (int d2 = 0; d2 < 3; ++d2)
      #pragma unroll
      for (int d3 = 0; d3 < 3; ++d3) {
        const int idx = ((z1 + d1) * 4 + (z2 + d2)) * 66 + (z3 + d3);
        mx = fmaxf(mx, a2x[idx]);
        mo = fmaxf(mo, a2o[idx]);
      }
  const bool life = (mx > 0.1f) && (mo > 0.1f);
  if (!life) {
    const int gv = ((b * 64 + z1base + z1) * 64 + (z2base + z2)) * 64 + z3;
    f32x4 z = {0.f, 0.f, 0.f, 0.f};
    #pragma unroll
    for (int j = 0; j < 4; ++j) *(f32x4*)(og + gv * 16 + j * 4) = z;
  }
}

extern "C" void kernel_launch(void* const* d_in, const int* in_sizes, int n_in,
                              void* d_out, int out_size, void* d_ws, size_t ws_size,
                              hipStream_t stream) {
  (void)out_size;
  const void *px = nullptr, *pw0 = nullptr, *pb0 = nullptr, *pw1 = nullptr, *pst = nullptr;
  for (int i = 0; i < n_in; ++i) {
    switch (in_sizes[i]) {
      case 16777216: px  = d_in[i]; break;  // x  [4,64,64,64,16]
      case 8192:     pw0 = d_in[i]; break;  // w0 [128,64]
      case 128:      pb0 = d_in[i]; break;  // b0 [128]
      case 2048:     pw1 = d_in[i]; break;  // w1 [16,128]
      case 1048576:  pst = d_in[i]; break;  // stoch [4,64,64,64,1]
    }
  }
  if (!px || !pw0 || !pb0 || !pw1 || !pst) {
    px = d_in[0]; pw0 = d_in[1]; pb0 = d_in[2]; pw1 = d_in[3]; pst = d_in[4];
  }
  float* outg = (float*)d_out;
  const size_t need = (size_t)VTOT * 4 + (size_t)VTOT;  // fp32 z3-max alpha + byte plife
  const bool use_ws = (d_ws != nullptr) && (ws_size >= need);
  float* aws = use_ws ? (float*)d_ws : nullptr;
  unsigned char* plife = use_ws ? ((unsigned char*)d_ws + (size_t)VTOT * 4) : nullptr;

  nca_main<<<4096, 256, 0, stream>>>((const float*)px, (const float*)pw0, (const float*)pb0,
                                     (const float*)pw1, (const float*)pst, outg, aws, plife);
  if (use_ws)
    nca_life<<<4096, 256, 0, stream>>>(aws, plife, outg);
  else
    nca_life_strided<<<4096, 256, 0, stream>>>((const float*)px, outg, outg);
}

// Round 4
// 273.118 us; speedup vs baseline: 2.2131x; 1.3079x over previous
//
#include <hip/hip_runtime.h>
#include <hip/hip_bf16.h>

typedef unsigned short u16t;
typedef __attribute__((ext_vector_type(8))) short short8;
typedef __attribute__((ext_vector_type(8))) unsigned short ushort8;
typedef __attribute__((ext_vector_type(4))) unsigned short ushort4v;
typedef __attribute__((ext_vector_type(4))) float f32x4;

#define VTOT 1048576

__device__ __forceinline__ float bf2f(u16t u) {
  union { unsigned int i; float f; } v; v.i = ((unsigned int)u) << 16; return v.f;
}
__device__ __forceinline__ u16t f2bf(float f) {
  __hip_bfloat16 h = __float2bfloat16(f);
  union { __hip_bfloat16 b; u16t u; } v; v.b = h; return v.u;
}

// Kernel 1: sobel conv (bf16 LDS, fp32 accum) + fc0(relu) + fc1 via bf16 MFMA + stoch mask.
// R6: N-split fc0 across waves + swapped-operand MFMA (h^T C-layout) so the whole
// per-wave h slice (128 vox x 32 cols) lives in 32 VGPRs of bf16.  Register peak
// drops ~150 -> ~100 (goal: unified VGPR+AGPR <= 128 -> 4 waves/SIMD; R0/R5 sat at
// 2 blocks/CU because the GEMM register set crossed the 128 cliff — rocprof's
// VGPR_Count under-reports the accumulator share).  h exchange via one overlay
// buffer [128][136] bf16 on top of xs+ys (both dead), 2 barriers per GEMM.
// LDS 37.1KB -> 4 blocks/CU by LDS.  lb(256,2): do NOT constrain the allocator
// (R4: lb(256,4) forced 64 VGPR -> 1.6GB spill traffic).
__global__ __launch_bounds__(256, 2) void nca_main(
    const float* __restrict__ xg, const float* __restrict__ w0g,
    const float* __restrict__ b0g, const float* __restrict__ w1g,
    const float* __restrict__ stg, float* __restrict__ outg,
    float* __restrict__ aws, unsigned char* __restrict__ plife)
{
  // smem carve: [0..8704) u16 = xs halo [4][4][34][16]; [8704..16896) u16 = ys
  // [8 kchunks][128 vox][8]; whole [0..17408) u16 reused as h [128 vox][136] bf16.
  __shared__ u16t smem[17408];
  __shared__ float st_l[256];        // stoch fp32
  __shared__ float alpha_l[256];     // fp32 alpha(x2), staged for z3-max + coalesced aws flush
  __shared__ unsigned char pl_l[256];// pre_life bits

  const int t = threadIdx.x;
  const int bid = blockIdx.x;
  const int b = bid >> 10;
  const int z1base = ((bid >> 5) & 31) * 2;
  const int z2base = (bid & 31) * 2;

  {
    int z1 = t >> 7, z2 = (t >> 6) & 1, z3 = t & 63;
    int gv = ((b * 64 + z1base + z1) * 64 + (z2base + z2)) * 64 + z3;
    st_l[t] = stg[gv];
  }

  #pragma unroll 1
  for (int p = 0; p < 2; ++p) {
    asm volatile("" ::: "memory");
    if (p) __syncthreads();  // smem WAR vs previous pass fc1 h reads
    // stage x halo (fp32 -> bf16): 544 rows x 16 ch = 2176 float4 chunks
    for (int it = 0; it < 9; ++it) {
      int q = t + it * 256;
      if (q < 2176) {
        int c4 = (q & 3) * 4, s = q >> 2;
        int i3 = s % 34, r = s / 34;
        int i2 = r & 3, i1 = r >> 2;
        int z1g = z1base + i1 - 1, z2g = z2base + i2 - 1, z3g = p * 32 + i3 - 1;
        f32x4 val = {0.f, 0.f, 0.f, 0.f};
        if ((unsigned)z1g < 64u && (unsigned)z2g < 64u && (unsigned)z3g < 64u) {
          int gv = ((b * 64 + z1g) * 64 + z2g) * 64 + z3g;
          val = *(const f32x4*)(xg + gv * 16 + c4);
        }
        ushort4v bv;
        #pragma unroll
        for (int j = 0; j < 4; ++j) bv[j] = f2bf(val[j]);
        *(ushort4v*)(smem + s * 16 + c4) = bv;
      }
    }
    __syncthreads();
    // conv: one (voxel, channel-half) per thread; 128 voxels this pass
    {
      const int hc = t & 1, vp = t >> 1;
      const int z1 = vp >> 6, z2 = (vp >> 5) & 1, z3l = vp & 31;
      float ax[8], ay[8], az[8];
      #pragma unroll
      for (int c = 0; c < 8; ++c) { ax[c] = 0.f; ay[c] = 0.f; az[c] = 0.f; }
      ushort8 ctr{};
      float amax = 0.0f;  // alpha>=0 in x; 0-pad gives same >0.1 verdict as -inf pad
      const float W[3] = {1.f, 2.f, 1.f};
      const float D[3] = {-1.f, 0.f, 1.f};
      #pragma unroll
      for (int d1 = 0; d1 < 3; ++d1)
        #pragma unroll
        for (int d2 = 0; d2 < 3; ++d2)
          #pragma unroll
          for (int d3 = 0; d3 < 3; ++d3) {
            const int base = (((z1 + d1) * 4 + (z2 + d2)) * 34 + (z3l + d3)) * 16 + hc * 8;
            ushort8 u = *(const ushort8*)(smem + base);
            float f[8];
            #pragma unroll
            for (int c = 0; c < 8; ++c) f[c] = bf2f((u16t)u[c]);
            const float cx = W[d1] * W[d2] * D[d3] * 0.03125f;  // kx[k,i,j]=w[k]w[i]d[j]/32
            const float cy = W[d1] * D[d2] * W[d3] * 0.03125f;  // ky=kx.T(0,2,1)
            const float cz = D[d1] * W[d2] * W[d3] * 0.03125f;  // kz=kx.T(2,1,0)
            if (cx != 0.f) {
              #pragma unroll
              for (int c = 0; c < 8; ++c) ax[c] = fmaf(f[c], cx, ax[c]);
            }
            if (cy != 0.f) {
              #pragma unroll
              for (int c = 0; c < 8; ++c) ay[c] = fmaf(f[c], cy, ay[c]);
            }
            if (cz != 0.f) {
              #pragma unroll
              for (int c = 0; c < 8; ++c) az[c] = fmaf(f[c], cz, az[c]);
            }
            if (d1 == 1 && d2 == 1 && d3 == 1) ctr = u;
            amax = fmaxf(amax, f[3]);  // alpha = ch3 (meaningful for hc==0)
          }
      *(ushort8*)(smem + 8704 + (0 + hc) * 1024 + vp * 8) = ctr;
      ushort8 bx, by, bz;
      #pragma unroll
      for (int c = 0; c < 8; ++c) {
        bx[c] = (short)f2bf(ax[c]); by[c] = (short)f2bf(ay[c]); bz[c] = (short)f2bf(az[c]);
      }
      *(ushort8*)(smem + 8704 + (2 + hc) * 1024 + vp * 8) = bx;
      *(ushort8*)(smem + 8704 + (4 + hc) * 1024 + vp * 8) = by;
      *(ushort8*)(smem + 8704 + (6 + hc) * 1024 + vp * 8) = bz;
      if (hc == 0) pl_l[z1 * 128 + z2 * 64 + p * 32 + z3l] = (amax > 0.1f) ? (unsigned char)1 : (unsigned char)0;
    }
    __syncthreads();  // conv ys writes visible; xs halo now dead

    // GEMM phase, N-split: wave w owns h cols [w*32, w*32+32) for all 128 voxels.
    // fc0 swapped MFMA: D = mfma(A=w0f, B=yf) -> lane holds h[n=w*32+nt*16+quad*4+r][vox=mt*16+col].
    {
      const int lane = t & 63, w = t >> 6;
      const int col = lane & 15, quad = lane >> 4;
      // A-operand frags: w0f[kt][nt][j] = w0[w*32+nt*16+col][kt*32+quad*8+j]
      short8 w0f[2][2];
      #pragma unroll
      for (int kt = 0; kt < 2; ++kt)
        #pragma unroll
        for (int nt = 0; nt < 2; ++nt) {
          const float* pw = w0g + (w * 32 + nt * 16 + col) * 64 + kt * 32 + quad * 8;
          f32x4 lo = *(const f32x4*)pw, hi = *(const f32x4*)(pw + 4);
          short8 fr;
          #pragma unroll
          for (int j = 0; j < 4; ++j) { fr[j] = (short)f2bf(lo[j]); fr[4 + j] = (short)f2bf(hi[j]); }
          w0f[kt][nt] = fr;
        }
      // bias along the row (n) dim: biasv[nt][r] = b0[w*32+nt*16+quad*4+r]
      f32x4 biasv[2];
      #pragma unroll
      for (int nt = 0; nt < 2; ++nt)
        biasv[nt] = *(const f32x4*)(b0g + w * 32 + nt * 16 + quad * 4);

      ushort4v hpk[8][2];  // per-wave h slice, bf16-packed: 32 VGPRs
      #pragma unroll
      for (int mt = 0; mt < 8; ++mt) {
        short8 yf[2];  // B-operand: yf[kt][j] = y[mt*16+col][kt*32+quad*8+j]
        #pragma unroll
        for (int kt = 0; kt < 2; ++kt)
          yf[kt] = *(const short8*)(smem + 8704 + (kt * 4 + quad) * 1024 + (mt * 16 + col) * 8);
        f32x4 acc[2];
        acc[0] = biasv[0]; acc[1] = biasv[1];
        #pragma unroll
        for (int kt = 0; kt < 2; ++kt)
          #pragma unroll
          for (int nt = 0; nt < 2; ++nt)
            acc[nt] = __builtin_amdgcn_mfma_f32_16x16x32_bf16(w0f[kt][nt], yf[kt], acc[nt], 0, 0, 0);
        #pragma unroll
        for (int nt = 0; nt < 2; ++nt) {
          ushort4v hv;
          #pragma unroll
          for (int r = 0; r < 4; ++r) hv[r] = f2bf(fmaxf(acc[nt][r], 0.0f));
          hpk[mt][nt] = hv;
        }
      }
      __syncthreads();  // all ys reads done (every wave) before h overlay clobbers smem
      // h dump: h[vox=mt*16+col][n=w*32+nt*16+quad*4 + 0..3] -> one b64 per (mt,nt)
      #pragma unroll
      for (int mt = 0; mt < 8; ++mt)
        #pragma unroll
        for (int nt = 0; nt < 2; ++nt)
          *(ushort4v*)(smem + (mt * 16 + col) * 136 + w * 32 + nt * 16 + quad * 4) = hpk[mt][nt];
      __syncthreads();  // h visible to all waves (fc1 reads all n for its voxels)

      // fc1: wave w handles voxels [w*32, w*32+32); K=128, N=16
      short8 w1f[4];  // B[k][n=col] = w1[col][k]
      #pragma unroll
      for (int kt = 0; kt < 4; ++kt) {
        const float* pw = w1g + col * 128 + kt * 32 + quad * 8;
        f32x4 lo = *(const f32x4*)pw, hi = *(const f32x4*)(pw + 4);
        short8 fr;
        #pragma unroll
        for (int j = 0; j < 4; ++j) { fr[j] = (short)f2bf(lo[j]); fr[4 + j] = (short)f2bf(hi[j]); }
        w1f[kt] = fr;
      }
      #pragma unroll
      for (int mt = 0; mt < 2; ++mt) {
        const int mbase = w * 32 + mt * 16;
        f32x4 dxa = {0.f, 0.f, 0.f, 0.f};
        #pragma unroll
        for (int kt = 0; kt < 4; ++kt) {
          short8 ah = *(const short8*)(smem + (mbase + col) * 136 + kt * 32 + quad * 8);
          dxa = __builtin_amdgcn_mfma_f32_16x16x32_bf16(ah, w1f[kt], dxa, 0, 0, 0);
        }
        // epilogue: out[v][col] = x[v][col] + mask*dx (xg re-read is L2/L3-hot)
        #pragma unroll
        for (int r = 0; r < 4; ++r) {
          const int vp = mbase + quad * 4 + r;
          const int z1 = vp >> 6, z2 = (vp >> 5) & 1, z3l = vp & 31;
          const int v = z1 * 128 + z2 * 64 + p * 32 + z3l;
          const int gv = ((b * 64 + z1base + z1) * 64 + (z2base + z2)) * 64 + p * 32 + z3l;
          const int addr = gv * 16 + col;
          float dx = (st_l[v] > 0.5f) ? dxa[r] : 0.0f;
          float x2 = xg[addr] + dx;
          outg[addr] = x2;
          if (col == 3) alpha_l[v] = x2;  // stage fp32 alpha(x2) in LDS
        }
      }
    }
  }
  __syncthreads();
  // coalesced aux flush; fold the z3 direction of the alive maxpool here:
  // aws[gv] = max(alpha[z3-1], alpha[z3], alpha[z3+1]) (domain edges -> -1e30 sentinel)
  if (aws != nullptr) {
    const int v = t, z3 = t & 63;
    const float a = alpha_l[v];
    const float up = (z3 > 0) ? alpha_l[v - 1] : -1e30f;
    const float dn = (z3 < 63) ? alpha_l[v + 1] : -1e30f;
    const int gv = ((b * 64 + z1base + (v >> 7)) * 64 + (z2base + ((v >> 6) & 1))) * 64 + z3;
    aws[gv] = fmaxf(a, fmaxf(up, dn));
    plife[gv] = pl_l[v];
  }
}

// Kernel 2: life = plife & (max over 3x3 (z1,z2) rows of z3-premaxed aws > 0.1);
// zero dead voxels in out.  Staging is 16 fully-coalesced 256B rows, no div/mod.
__global__ void nca_life(const float* __restrict__ aws,
                         const unsigned char* __restrict__ plife,
                         float* __restrict__ og)
{
  __shared__ float m3s[1024];  // [16 rows][64] z3-premaxed alpha(x2)
  const int t = threadIdx.x, bid = blockIdx.x;
  const int b = bid >> 10;
  const int z1base = ((bid >> 5) & 31) * 2;
  const int z2base = (bid & 31) * 2;
  #pragma unroll
  for (int it = 0; it < 4; ++it) {
    const int row = it * 4 + (t >> 6), z3 = t & 63;
    const int z1g = z1base + (row >> 2) - 1, z2g = z2base + (row & 3) - 1;
    float a = -1e30f;
    if ((unsigned)z1g < 64u && (unsigned)z2g < 64u)
      a = aws[((b * 64 + z1g) * 64 + z2g) * 64 + z3];
    m3s[row * 64 + z3] = a;
  }
  const int z1 = t >> 7, z2 = (t >> 6) & 1, z3 = t & 63;
  const int gv = ((b * 64 + z1base + z1) * 64 + (z2base + z2)) * 64 + z3;
  const unsigned char pl = plife[gv];  // issue early, hide under barrier
  __syncthreads();
  float mo = -1e30f;
  #pragma unroll
  for (int d1 = 0; d1 < 3; ++d1)
    #pragma unroll
    for (int d2 = 0; d2 < 3; ++d2)
      mo = fmaxf(mo, m3s[((z1 + d1) * 4 + (z2 + d2)) * 64 + z3]);
  const bool life = (pl != 0) && (mo > 0.1f);
  if (!life) {
    f32x4 z = {0.f, 0.f, 0.f, 0.f};
    #pragma unroll
    for (int j = 0; j < 4; ++j) *(f32x4*)(og + gv * 16 + j * 4) = z;
  }
}

// Fallback (no workspace): recompute both alive masks from strided global reads.
__global__ void nca_life_strided(const float* __restrict__ xg, const float* __restrict__ outg,
                                 float* __restrict__ og)
{
  __shared__ float a2x[1056];
  __shared__ float a2o[1056];
  const int t = threadIdx.x, bid = blockIdx.x;
  const int b = bid >> 10;
  const int z1base = ((bid >> 5) & 31) * 2;
  const int z2base = (bid & 31) * 2;
  for (int it = 0; it < 5; ++it) {
    int q = t + it * 256;
    if (q < 1056) {
      int i3 = q % 66, r = q / 66;
      int i2 = r & 3, i1 = r >> 2;
      int z1g = z1base + i1 - 1, z2g = z2base + i2 - 1, z3g = i3 - 1;
      float vx = 0.f, vo = 0.f;
      if ((unsigned)z1g < 64u && (unsigned)z2g < 64u && (unsigned)z3g < 64u) {
        int gv = ((b * 64 + z1g) * 64 + z2g) * 64 + z3g;
        vx = xg[gv * 16 + 3];
        vo = outg[gv * 16 + 3];
      }
      a2x[q] = vx; a2o[q] = vo;
    }
  }
  __syncthreads();
  const int z1 = t >> 7, z2 = (t >> 6) & 1, z3 = t & 63;
  float mx = -1e30f, mo = -1e30f;
  #pragma unroll
  for (int d1 = 0; d1 < 3; ++d1)
    #pragma unroll
    for (int d2 = 0; d2 < 3; ++d2)
      #pragma unroll
      for (int d3 = 0; d3 < 3; ++d3) {
        const int idx = ((z1 + d1) * 4 + (z2 + d2)) * 66 + (z3 + d3);
        mx = fmaxf(mx, a2x[idx]);
        mo = fmaxf(mo, a2o[idx]);
      }
  const bool life = (mx > 0.1f) && (mo > 0.1f);
  if (!life) {
    const int gv = ((b * 64 + z1base + z1) * 64 + (z2base + z2)) * 64 + z3;
    f32x4 z = {0.f, 0.f, 0.f, 0.f};
    #pragma unroll
    for (int j = 0; j < 4; ++j) *(f32x4*)(og + gv * 16 + j * 4) = z;
  }
}

extern "C" void kernel_launch(void* const* d_in, const int* in_sizes, int n_in,
                              void* d_out, int out_size, void* d_ws, size_t ws_size,
                              hipStream_t stream) {
  (void)out_size;
  const void *px = nullptr, *pw0 = nullptr, *pb0 = nullptr, *pw1 = nullptr, *pst = nullptr;
  for (int i = 0; i < n_in; ++i) {
    switch (in_sizes[i]) {
      case 16777216: px  = d_in[i]; break;  // x  [4,64,64,64,16]
      case 8192:     pw0 = d_in[i]; break;  // w0 [128,64]
      case 128:      pb0 = d_in[i]; break;  // b0 [128]
      case 2048:     pw1 = d_in[i]; break;  // w1 [16,128]
      case 1048576:  pst = d_in[i]; break;  // stoch [4,64,64,64,1]
    }
  }
  if (!px || !pw0 || !pb0 || !pw1 || !pst) {
    px = d_in[0]; pw0 = d_in[1]; pb0 = d_in[2]; pw1 = d_in[3]; pst = d_in[4];
  }
  float* outg = (float*)d_out;
  const size_t need = (size_t)VTOT * 4 + (size_t)VTOT;  // fp32 z3-max alpha + byte plife
  const bool use_ws = (d_ws != nullptr) && (ws_size >= need);
  float* aws = use_ws ? (float*)d_ws : nullptr;
  unsigned char* plife = use_ws ? ((unsigned char*)d_ws + (size_t)VTOT * 4) : nullptr;

  nca_main<<<4096, 256, 0, stream>>>((const float*)px, (const float*)pw0, (const float*)pb0,
                                     (const float*)pw1, (const float*)pst, outg, aws, plife);
  if (use_ws)
    nca_life<<<4096, 256, 0, stream>>>(aws, plife, outg);
  else
    nca_life_strided<<<4096, 256, 0, stream>>>((const float*)px, outg, outg);
}